// Round 22
// baseline (14546.744 us; speedup 1.0000x reference)
//
#include <hip/hip_runtime.h>
#include <math.h>

#pragma clang fp contract(off)

#define NB 2048
#define NC 1000
#define NK 2048

// ---------------- GEMM: fp32 fold-left ascending-k with K-panel folds of PC chunks ------
// PC = panel size in 16-wide chunks (0 = monolithic). Panel partials folded left into C.
__global__ __launch_bounds__(256) void k_gemm(const float* __restrict__ x,
                                              const float* __restrict__ W,
                                              const float* __restrict__ bias,
                                              float* __restrict__ z, int PC) {
    __shared__ float As[16][64];
    __shared__ float Bs[16][64];
    const int tid = threadIdx.x;
    const int m0 = blockIdx.y * 64, n0 = blockIdx.x * 64;
    const int tx = tid & 15, ty = tid >> 4;
    float accT[4][4];
    float accB[4][4];
#pragma unroll
    for (int i = 0; i < 4; i++)
#pragma unroll
        for (int j = 0; j < 4; j++) { accT[i][j] = 0.0f; accB[i][j] = 0.0f; }

    for (int kb = 0; kb < 128; kb++) {
        if (PC > 0 && kb > 0 && (kb % PC) == 0) {
#pragma unroll
            for (int i = 0; i < 4; i++)
#pragma unroll
                for (int j = 0; j < 4; j++) { accT[i][j] += accB[i][j]; accB[i][j] = 0.0f; }
        }
        const int k0 = kb * 16;
        {
            int row = tid >> 2, kg = tid & 3;
            const float4 a = *(const float4*)(x + (size_t)(m0 + row) * NK + k0 + kg * 4);
            As[kg * 4 + 0][row] = a.x;
            As[kg * 4 + 1][row] = a.y;
            As[kg * 4 + 2][row] = a.z;
            As[kg * 4 + 3][row] = a.w;
        }
        {
            int rowk = tid >> 4, c4 = tid & 15;
            int cbase = n0 + c4 * 4;
            const float* wp = W + (size_t)(k0 + rowk) * NC + cbase;
#pragma unroll
            for (int j = 0; j < 4; j++)
                Bs[rowk][c4 * 4 + j] = (cbase + j < NC) ? wp[j] : 0.0f;
        }
        __syncthreads();
#pragma unroll
        for (int kk = 0; kk < 16; kk++) {
            float a[4], bb[4];
#pragma unroll
            for (int i = 0; i < 4; i++) a[i] = As[kk][ty * 4 + i];
#pragma unroll
            for (int j = 0; j < 4; j++) bb[j] = Bs[kk][tx * 4 + j];
#pragma unroll
            for (int i = 0; i < 4; i++)
#pragma unroll
                for (int j = 0; j < 4; j++) accB[i][j] = fmaf(a[i], bb[j], accB[i][j]);
        }
        __syncthreads();
    }
#pragma unroll
    for (int i = 0; i < 4; i++) {
        int r = m0 + ty * 4 + i;
#pragma unroll
        for (int j = 0; j < 4; j++) {
            int c = n0 + tx * 4 + j;
            if (c < NC) {
                float s = accT[i][j] + accB[i][j];
                z[(size_t)r * NC + c] = s + bias[c];
            }
        }
    }
}

// ---------------- per-row stats ----------------
__global__ __launch_bounds__(256) void k_rowstats(const float* __restrict__ z,
                                                  int* __restrict__ y,
                                                  float* __restrict__ ptrg,
                                                  float* __restrict__ se,
                                                  float* __restrict__ rm,
                                                  int* __restrict__ am) {
    __shared__ float sv[256];
    __shared__ int si[256];
    const int tid = threadIdx.x, row = blockIdx.x;
    const float* zr = z + (size_t)row * NC;
    float bv = -INFINITY;
    int bi = 0x7fffffff;
    for (int c = tid; c < NC; c += 256) {
        float zz = zr[c];
        if (zz > bv) { bv = zz; bi = c; }
    }
    sv[tid] = bv; si[tid] = bi;
    __syncthreads();
    for (int s = 128; s > 0; s >>= 1) {
        if (tid < s) {
            float v2 = sv[tid + s]; int i2 = si[tid + s];
            if (v2 > sv[tid] || (v2 == sv[tid] && i2 < si[tid])) { sv[tid] = v2; si[tid] = i2; }
        }
        __syncthreads();
    }
    const float rmx = sv[0];
    const int amx = si[0];
    __syncthreads();
    float sl = 0.0f;
    for (int c = tid; c < NC; c += 256) sl += expf(zr[c] - rmx);
    sv[tid] = sl;
    __syncthreads();
    for (int s = 128; s > 0; s >>= 1) {
        if (tid < s) sv[tid] += sv[tid + s];
        __syncthreads();
    }
    if (tid == 0) {
        float s0 = sv[0];
        y[row] = amx; ptrg[row] = 1.0f / s0;
        se[row] = s0; rm[row] = rmx; am[row] = amx;
    }
}

__global__ void k_hist(const int* __restrict__ y, int* __restrict__ cnt) {
    int i = blockIdx.x * 256 + threadIdx.x;
    if (i < NB) atomicAdd(&cnt[y[i]], 1);
}
__global__ __launch_bounds__(1024) void k_group(const int* __restrict__ y,
                                                const int* __restrict__ cnt,
                                                int* __restrict__ off,
                                                int* __restrict__ pos,
                                                int* __restrict__ jidx) {
    __shared__ int s[1024];
    const int tid = threadIdx.x;
    int myc = (tid < NC) ? cnt[tid] : 0;
    s[tid] = myc;
    __syncthreads();
    for (int d = 1; d < 1024; d <<= 1) {
        int add = (tid >= d) ? s[tid - d] : 0;
        __syncthreads();
        s[tid] += add;
        __syncthreads();
    }
    if (tid < NC) {
        int excl = s[tid] - myc;
        off[tid] = excl;
        pos[tid] = excl;
    }
    if (tid == 0) off[NC] = NB;
    __syncthreads();
    for (int j = tid; j < NB; j += 1024) {
        int c = y[j];
        int p = atomicAdd(&pos[c], 1);
        jidx[p] = j;
    }
}

__global__ __launch_bounds__(256) void k_preptz(const float* __restrict__ z,
                                                const int* __restrict__ cnt,
                                                float* __restrict__ u,
                                                float* __restrict__ tz,
                                                float* __restrict__ tu) {
    __shared__ float sv[256];
    const int tid = threadIdx.x, row = blockIdx.x;
    const float* zr = z + (size_t)row * NC;
    float tm = -1000.0f;
    for (int c = tid; c < NC; c += 256) {
        float zz = zr[c];
        if (cnt[c] == 0) tm = fmaxf(tm, zz);
        u[(size_t)row * NC + c] = zz;
    }
    sv[tid] = tm;
    __syncthreads();
    for (int s = 128; s > 0; s >>= 1) {
        if (tid < s) sv[tid] = fmaxf(sv[tid], sv[tid + s]);
        __syncthreads();
    }
    if (tid == 0) { tz[row] = sv[0]; tu[row] = sv[0]; }
}

__global__ __launch_bounds__(256) void k_thr(const float* __restrict__ z,
                                             const float* __restrict__ tz,
                                             const int* __restrict__ y,
                                             const int* __restrict__ jidx,
                                             float* __restrict__ ThrG) {
    const int tid = threadIdx.x, a = blockIdx.x;
    const float PIF = 3.14159265358979323846f;
    const float* zr = z + (size_t)a * NC;
    for (int p = tid; p < NB; p += 256) {
        int j = jidx[p];
        int c = y[j];
        float L = zr[c] - tz[j];
        float q = L / 6.0f;
        float fq = floorf(q);
        float fh = fq + 0.5f;
        float latr = fh * 6.0f;
        float d1 = L - latr;
        float d2 = 2.0f * d1;
        float d3 = d2 / 6.0f;
        float d4 = 1.0f - d3;
        float d5 = PIF * d4;
        float sn = sinf(d5);
        float p6 = 6.0f * sn;
        float thr = L - p6;
        ThrG[(size_t)a * NB + p] = thr;
    }
}

// ---------------- one Adam step (OCML arithmetic) ----------------
__global__ __launch_bounds__(256) void k_step(float* __restrict__ u,
                                              float* __restrict__ m,
                                              float* __restrict__ v,
                                              const float* __restrict__ ThrG,
                                              const float* __restrict__ ptrg,
                                              const int* __restrict__ cnt,
                                              const int* __restrict__ off,
                                              const int* __restrict__ jidx,
                                              const float* __restrict__ seO,
                                              const float* __restrict__ rmO,
                                              const float* __restrict__ tuO,
                                              const int* __restrict__ amO,
                                              float* __restrict__ seN,
                                              float* __restrict__ rmN,
                                              float* __restrict__ tuN,
                                              int* __restrict__ amN,
                                              float bc1, float bc2) {
    __shared__ float tuG[NB];
    __shared__ float sv[256];
    __shared__ int si[256];
    __shared__ float fbc[2];
    __shared__ int ibc[1];
    const int tid = threadIdx.x, row = blockIdx.x;
    const float B1F = 0.9f;
    const float C1 = (float)(1.0 - 0.9);
    const float B2F = 0.999f;
    const float C2 = (float)(1.0 - 0.999);

    for (int p = tid; p < NB; p += 256) tuG[p] = tuO[jidx[p]];

    float bv = -INFINITY;
    int bi = 0x7fffffff;
    for (int i = tid; i < NB; i += 256) {
        float p = 1.0f / seO[i];
        if (p > bv || (p == bv && i < bi)) { bv = p; bi = i; }
    }
    sv[tid] = bv; si[tid] = bi;
    __syncthreads();
    for (int s = 128; s > 0; s >>= 1) {
        if (tid < s) {
            float v2 = sv[tid + s]; int i2 = si[tid + s];
            if (v2 > sv[tid] || (v2 == sv[tid] && i2 < si[tid])) { sv[tid] = v2; si[tid] = i2; }
        }
        __syncthreads();
    }
    const float pmax = sv[0];
    const int istar = si[0];
    __syncthreads();
    float s2l = 0.0f;
    for (int i = tid; i < NB; i += 256) {
        float d = pmax - ptrg[i];
        s2l += (d >= 0.0f) ? 1.0f : -1.0f;
    }
    sv[tid] = s2l;
    __syncthreads();
    for (int s = 128; s > 0; s >>= 1) {
        if (tid < s) sv[tid] += sv[tid + s];
        __syncthreads();
    }
    const float s2 = sv[0];
    if (tid == 0) {
        fbc[0] = seO[istar];
        fbc[1] = rmO[istar];
        ibc[0] = amO[istar];
    }
    __syncthreads();
    const float se_i = fbc[0], rm_i = fbc[1];
    const int jstar = ibc[0];
    const float Kf = 5.0f * (2048.0f * s2);
    const float coef = Kf * pmax;
    const bool ig2 = (row == istar);

    float uu[4];
    int cns[4];
    float nmax = -INFINITY;
    int nidx = 0x7fffffff;
    float ntop = -1000.0f;
    const size_t base = (size_t)row * NC;
    const size_t tbase = (size_t)row * NB;
#pragma unroll
    for (int k2 = 0; k2 < 4; k2++) {
        int c = tid + k2 * 256;
        uu[k2] = 0.0f; cns[k2] = -1;
        if (c < NC) {
            float u0 = u[base + c];
            float mm = m[base + c];
            float vv = v[base + c];
            int cn = cnt[c];
            int p0 = off[c], p1 = off[c + 1];
            float g = 0.0f;
            for (int p = p0; p < p1; p++) {
                float marg = u0 - tuG[p];
                float diff = marg - ThrG[tbase + p];
                g += (diff >= 0.0f) ? 1.0f : -1.0f;
            }
            if (ig2) {
                float e = expf(u0 - rm_i);
                float S = e / se_i;
                float dlt = ((c == jstar) ? 1.0f : 0.0f) - S;
                float t2v = coef * dlt;
                g = g + t2v;
            }
            float t1m = B1F * mm;
            float t2m = C1 * g;
            mm = t1m + t2m;
            float gg1 = C2 * g;
            float gg2 = gg1 * g;
            float t1v = B2F * vv;
            vv = t1v + gg2;
            float mh = mm / bc1;
            float vh = vv / bc2;
            float num = 0.1f * mh;
            float sq = sqrtf(vh);
            float den = sq + 1e-8f;
            float qq = num / den;
            u0 = u0 - qq;
            u[base + c] = u0;
            m[base + c] = mm;
            v[base + c] = vv;
            uu[k2] = u0; cns[k2] = cn;
            if (u0 > nmax || (u0 == nmax && c < nidx)) { nmax = u0; nidx = c; }
            if (cn == 0) ntop = fmaxf(ntop, u0);
        }
    }
    __syncthreads();
    sv[tid] = nmax; si[tid] = nidx;
    __syncthreads();
    for (int s = 128; s > 0; s >>= 1) {
        if (tid < s) {
            float v2 = sv[tid + s]; int i2 = si[tid + s];
            if (v2 > sv[tid] || (v2 == sv[tid] && i2 < si[tid])) { sv[tid] = v2; si[tid] = i2; }
        }
        __syncthreads();
    }
    const float rm_n = sv[0];
    const int am_n = si[0];
    __syncthreads();
    sv[tid] = ntop;
    __syncthreads();
    for (int s = 128; s > 0; s >>= 1) {
        if (tid < s) sv[tid] = fmaxf(sv[tid], sv[tid + s]);
        __syncthreads();
    }
    const float tu_n = sv[0];
    __syncthreads();
    float sel = 0.0f;
#pragma unroll
    for (int k2 = 0; k2 < 4; k2++)
        if (cns[k2] >= 0) sel += expf(uu[k2] - rm_n);
    sv[tid] = sel;
    __syncthreads();
    for (int s = 128; s > 0; s >>= 1) {
        if (tid < s) sv[tid] += sv[tid + s];
        __syncthreads();
    }
    if (tid == 0) {
        seN[row] = sv[0];
        rmN[row] = rm_n;
        tuN[row] = tu_n;
        amN[row] = am_n;
    }
}

// ---------------- fuse: out = A + clamp(median5(A,P1..P4) - A, +-0.08) ----------------
__global__ void k_fuse5(const float* __restrict__ a, const float* __restrict__ p1,
                        const float* __restrict__ p2, const float* __restrict__ p3,
                        const float* __restrict__ p4, float* __restrict__ out, int n) {
    const float CL = 0.08f;
    int i = blockIdx.x * 256 + threadIdx.x;
    if (i < n) {
        float v0 = a[i], v1 = p1[i], v2 = p2[i], v3 = p3[i], v4 = p4[i];
        float vv[5] = {v0, v1, v2, v3, v4};
        // insertion sort 5
#pragma unroll
        for (int k = 1; k < 5; k++) {
            float key = vv[k];
            int j = k - 1;
            while (j >= 0 && vv[j] > key) { vv[j + 1] = vv[j]; j--; }
            vv[j + 1] = key;
        }
        float med = vv[2];
        float d = med - v0;
        d = fminf(fmaxf(d, -CL), CL);
        out[i] = v0 + d;
    }
}

extern "C" void kernel_launch(void* const* d_in, const int* in_sizes, int n_in,
                              void* d_out, int out_size, void* d_ws, size_t ws_size,
                              hipStream_t stream) {
    (void)in_sizes; (void)n_in; (void)out_size; (void)ws_size;
    const float* x = (const float*)d_in[0];
    const float* W = (const float*)d_in[1];
    const float* bias = (const float*)d_in[2];
    float* out = (float*)d_out;

    const size_t NE = (size_t)NB * NC;
    float* zm   = (float*)d_ws;
    float* m32  = zm + NE;
    float* v32  = m32 + NE;
    float* t0   = v32 + NE;                 // 5 trajectory buffers
    float* t1   = t0 + NE;
    float* t2   = t1 + NE;
    float* t3   = t2 + NE;
    float* t4   = t3 + NE;
    float* ThrG = t4 + NE;                  // 2048*2048
    float* tz   = ThrG + (size_t)NB * NB;
    float* ptrg = tz + NB;
    float* seA  = ptrg + NB;
    float* rmA  = seA + NB;
    float* tuA  = rmA + NB;
    float* seB  = tuA + NB;
    float* rmB  = seB + NB;
    float* tuB  = rmB + NB;
    int* amA  = (int*)(tuB + NB);
    int* amB  = amA + NB;
    int* yv   = amB + NB;
    int* jidx = yv + NB;
    int* cnt  = jidx + NB;
    int* off  = cnt + 1024;
    int* pos  = off + 1024;

    float* traj[5] = {t0, t1, t2, t3, t4};
    const int PCs[5] = {0, 32, 24, 16, 10};   // monolithic, Kc=512,384,256,160
    const int nblk = (int)((NE + 255) / 256);

    for (int pass = 0; pass < 5; pass++) {
        k_gemm<<<dim3(16, 32), 256, 0, stream>>>(x, W, bias, zm, PCs[pass]);
        hipMemsetAsync(cnt, 0, 1024 * sizeof(int), stream);
        k_rowstats<<<NB, 256, 0, stream>>>(zm, yv, ptrg, seA, rmA, amA);
        k_hist<<<8, 256, 0, stream>>>(yv, cnt);
        k_group<<<1, 1024, 0, stream>>>(yv, cnt, off, pos, jidx);
        k_preptz<<<NB, 256, 0, stream>>>(zm, cnt, traj[pass], tz, tuA);
        k_thr<<<NB, 256, 0, stream>>>(zm, tz, yv, jidx, ThrG);
        hipMemsetAsync(m32, 0, NE * sizeof(float), stream);
        hipMemsetAsync(v32, 0, NE * sizeof(float), stream);
        for (int t = 1; t <= 100; t++) {
            float bc1 = 1.0f - powf(0.9f, (float)t);
            float bc2 = 1.0f - powf(0.999f, (float)t);
            const bool odd = (t & 1);
            k_step<<<NB, 256, 0, stream>>>(traj[pass], m32, v32, ThrG, ptrg, cnt, off, jidx,
                                           odd ? seA : seB, odd ? rmA : rmB,
                                           odd ? tuA : tuB, odd ? amA : amB,
                                           odd ? seB : seA, odd ? rmB : rmA,
                                           odd ? tuB : tuA, odd ? amB : amA,
                                           bc1, bc2);
        }
    }

    k_fuse5<<<nblk, 256, 0, stream>>>(t0, t1, t2, t3, t4, out, (int)NE);
}